// Round 6
// baseline (534.222 us; speedup 1.0000x reference)
//
#include <hip/hip_runtime.h>
#include <hip/hip_bf16.h>
#include <stdint.h>

typedef __hip_bfloat16 bf16;
typedef __attribute__((ext_vector_type(8))) short short8;
typedef __attribute__((ext_vector_type(4))) float f32x4;

#define SCALE_ 0.08838834764831845f  // 1/sqrt(128)

static __device__ __forceinline__ float bf2f(short u) {
  unsigned int x = ((unsigned int)(unsigned short)u) << 16;
  return __builtin_bit_cast(float, x);
}
static __device__ __forceinline__ short f2bf(float f) {
  __hip_bfloat16 h = __float2bfloat16(f);
  return __builtin_bit_cast(short, h);
}
static __device__ __forceinline__ f32x4 mfma16(short8 a, short8 b, f32x4 c) {
  return __builtin_amdgcn_mfma_f32_16x16x32_bf16(a, b, c, 0, 0, 0);
}
static __device__ __forceinline__ void gl_lds16(const bf16* g, bf16* l) {
  __builtin_amdgcn_global_load_lds(
      (const __attribute__((address_space(1))) unsigned int*)g,
      (__attribute__((address_space(3))) unsigned int*)l, 16, 0, 0);
}

// ---------------------------------------------------------------------------
// f32 -> bf16 conversion for x, wq, wk, wv, wo, prompt (one fused launch).
// ---------------------------------------------------------------------------
__global__ __launch_bounds__(256) void cvt6(
    const float* __restrict__ sx, const float* __restrict__ sq,
    const float* __restrict__ sk, const float* __restrict__ sv,
    const float* __restrict__ so, const float* __restrict__ sp,
    bf16* __restrict__ dx, bf16* __restrict__ dq, bf16* __restrict__ dk,
    bf16* __restrict__ dv, bf16* __restrict__ d4, bf16* __restrict__ dp)
{
  int b = blockIdx.x;
  const float* s; bf16* d; int off;
  if (b < 4096)       { s = sx; d = dx; off = b; }
  else if (b < 12288) { s = sq; d = dq; off = b - 4096; }
  else if (b < 20480) { s = sk; d = dk; off = b - 12288; }
  else if (b < 28672) { s = sv; d = dv; off = b - 20480; }
  else if (b < 36864) { s = so; d = d4; off = b - 28672; }
  else                { s = sp; d = dp; off = b - 36864; }
  long base = (long)off * 2048 + threadIdx.x * 8;
  f32x4 a = *(const f32x4*)(s + base);
  f32x4 c = *(const f32x4*)(s + base + 4);
  short8 o;
#pragma unroll
  for (int j = 0; j < 4; j++) { o[j] = f2bf(a[j]); o[4 + j] = f2bf(c[j]); }
  *(short8*)(d + base) = o;
}

// ---------------------------------------------------------------------------
// GEMM: C[m][n] = sum_k A[m][k] * Bw[n][k]  (A: MxK row-major, Bw: NxK row-major)
// 256x256 tile, BK=64, 8 waves (2m x 4n), per-wave 128x64.
// 8-phase schedule, DEPTH-6 prefetch (T3+T4): units of 16KB staged in fixed
// order u=0,1,2,... (unit u: tile u>>2, j=u&3 in {A-ks0,B-ks0,A-ks1,B-ks1},
// slot u&7, KE=(u>>2)*64+((u&2)?32:0)). Per tile t (phases g=4t+p):
//   p0: vmcnt(8)+barrier; stage u=4t+6; read A-ks0(mi0-3)+B-ks0; 16 MFMA
//   p1:                   stage u=4t+7; read A-ks0(mi4-7);       16 MFMA
//   p2: vmcnt(8)+barrier; stage u=4t+8; read A-ks1(mi0-3)+B-ks1; 16 MFMA
//   p3:                   stage u=4t+9; read A-ks1(mi4-7);       16 MFMA
// Invariant: wait at phase g certifies units <= (g-1+6)-4 = g+1 = newest unit
// read in {g, g+1} (derived per-phase; tail tiles use vmcnt(4)/vmcnt(0)).
// Units get 5 phases (~1250cy) to complete vs round-5's 3 (zero slack).
// WAR on slot reuse: unit u's stage follows a barrier that postdates the
// last read (phase <= u-7) of the evicted unit u-8  (D<=6 bound, equality).
// Barriers only at p0/p2: p1/p3 read only units certified at that barrier.
// LDS swizzle: slot s = (row&1)*4 + (c ^ ((row>>1)&3)) within 128B lines
// (2-way, free); gl_lds writes linearly, inverse perm on GLOBAL src (rule 21).
// Rows >= M1 come from A2 (prompt, clamped); outputs >= M1 go to Cp.
// CF != null -> f32 output (out-projection).
// ---------------------------------------------------------------------------
__global__ __launch_bounds__(512, 2) void gemm_bt(
    const bf16* __restrict__ A, const bf16* __restrict__ A2,
    const bf16* __restrict__ B0, const bf16* __restrict__ B1, const bf16* __restrict__ B2w,
    bf16* __restrict__ C0, bf16* __restrict__ C1, bf16* __restrict__ C2,
    bf16* __restrict__ P1, bf16* __restrict__ P2,
    float* __restrict__ CF,
    int M1, int Mtot)
{
  __shared__ char lds[131072];   // 8 slots x 16KB
  const int tid = threadIdx.x, w = tid >> 6, l = tid & 63;
  const int lr = l & 15, lg = l >> 4;
  const int wm = w >> 2, wn = w & 3;
  const int z = blockIdx.z;
  const bf16* Bw = (z == 0) ? B0 : ((z == 1) ? B1 : B2w);
  bf16* C  = (z == 0) ? C0 : ((z == 1) ? C1 : C2);
  bf16* Cp = (z == 0) ? (bf16*)0 : ((z == 1) ? P1 : P2);

  // T1: bijective chunked XCD swizzle (gridDim.x % 8 == 0), n fastest.
  const int cpx = gridDim.x >> 3, orig = blockIdx.x;
  const int wg = (orig & 7) * cpx + (orig >> 3);
  const long m0 = (long)(wg >> 4) * 256;
  const long n0 = (long)(wg & 15) * 256;

  // ---- staging source mapping (phys chunk P = tid, tid+512) ----
  // line = P>>3, s = P&7, row = 2*line + (s>>2), c = (s&3)^(line&3)
  const int r0 = ((tid >> 3) << 1) | ((tid >> 2) & 1);
  const int c0 = (tid & 3) ^ ((tid >> 3) & 3);
  const bf16 *pa0, *pa1;
  {
    long mx = (long)(Mtot - M1) - 1;
    long g0 = m0 + r0, g1 = m0 + r0 + 128;
    const bf16 *q0, *q1;
    if (g0 < M1) q0 = A + g0 * 4096;
    else { long rr = g0 - M1; if (rr > mx) rr = mx; q0 = A2 + rr * 4096; }
    if (g1 < M1) q1 = A + g1 * 4096;
    else { long rr = g1 - M1; if (rr > mx) rr = mx; q1 = A2 + rr * 4096; }
    pa0 = q0 + c0 * 8;
    pa1 = q1 + c0 * 8;
  }
  const bf16* pb0 = Bw + (n0 + r0) * 4096 + c0 * 8;
  const bf16* pb1 = pb0 + (long)128 * 4096;

  // ---- fragment-read offsets (swizzled; inverse of staging map) ----
  const int ro  = (lr >> 1) * 128 + (((lr & 1) * 4) + (lg ^ ((lr >> 1) & 3))) * 16;
  const int aro = wm * 8192 + ro;   // + mi*1024 within A unit
  const int bro = wn * 4096 + ro;   // + ni*1024 within B unit

  f32x4 acc[8][4];
#pragma unroll
  for (int i = 0; i < 8; i++)
#pragma unroll
    for (int j = 0; j < 4; j++) acc[i][j] = (f32x4){0.f, 0.f, 0.f, 0.f};

  short8 af[4], bf[4];

#define STGA(S_, KE_)                                                        \
  {                                                                          \
    bf16* d_ = (bf16*)(lds + (S_) * 16384) + tid * 8;                        \
    gl_lds16(pa0 + (KE_), d_);                                               \
    gl_lds16(pa1 + (KE_), d_ + 4096);                                        \
  }
#define STGB(S_, KE_)                                                        \
  {                                                                          \
    bf16* d_ = (bf16*)(lds + (S_) * 16384) + tid * 8;                        \
    gl_lds16(pb0 + (KE_), d_);                                               \
    gl_lds16(pb1 + (KE_), d_ + 4096);                                        \
  }
#define SYNC(VM_)                                                            \
  {                                                                          \
    asm volatile("s_waitcnt vmcnt(" VM_ ")" ::: "memory");                   \
    __builtin_amdgcn_s_barrier();                                            \
    __builtin_amdgcn_sched_barrier(0);                                       \
  }
#define PHASE(PRB_, AU_, BU_, MO_, LB_, STG_)                                \
  {                                                                          \
    STG_                                                                     \
    const char* ab_ = lds + (PRB_) + (AU_) + aro;                            \
    _Pragma("unroll") for (int mi = 0; mi < 4; mi++)                         \
      af[mi] = *(const short8*)(ab_ + ((MO_) + mi) * 1024);                  \
    if (LB_) {                                                               \
      const char* bb_ = lds + (PRB_) + (BU_) + bro;                          \
      _Pragma("unroll") for (int ni = 0; ni < 4; ni++)                       \
        bf[ni] = *(const short8*)(bb_ + ni * 1024);                          \
    }                                                                        \
    asm volatile("s_waitcnt lgkmcnt(0)" ::: "memory");                       \
    __builtin_amdgcn_sched_barrier(0);                                       \
    __builtin_amdgcn_s_setprio(1);                                           \
    _Pragma("unroll") for (int mi = 0; mi < 4; mi++)                         \
      _Pragma("unroll") for (int ni = 0; ni < 4; ni++)                       \
        acc[(MO_) + mi][ni] = mfma16(af[mi], bf[ni], acc[(MO_) + mi][ni]);   \
    __builtin_amdgcn_s_setprio(0);                                           \
  }

  // full-staging tile: reads parity PRB_, stages units into slots S6..S9
#define KT(PRB_, S6_, S7_, S8_, S9_, KE1_, KE2_)                             \
  SYNC("8") PHASE(PRB_, 0, 16384, 0, 1, STGA(S6_, KE1_))                     \
  PHASE(PRB_, 0, 16384, 4, 0, STGB(S7_, KE1_))                               \
  SYNC("8") PHASE(PRB_, 32768, 49152, 0, 1, STGA(S8_, KE2_))                 \
  PHASE(PRB_, 32768, 49152, 4, 0, STGB(S9_, KE2_))

  // prologue: units 0..5 (tile0 A0,B0,A1,B1 + tile1 A0,B0)
  STGA(0, 0) STGB(1, 0) STGA(2, 32) STGB(3, 32) STGA(4, 64) STGB(5, 64)

  // tiles 0..61 (full staging)
  for (int t = 0; t < 62; t += 2) {
    const int ka = (t + 1) * 64 + 32, kb = (t + 2) * 64;
    const int kc = (t + 2) * 64 + 32, kd = (t + 3) * 64;
    KT(0, 6, 7, 0, 1, ka, kb)        // tile t   (even, parity 0)
    KT(65536, 2, 3, 4, 5, kc, kd)    // tile t+1 (odd,  parity 1)
  }
  // tile 62 (parity 0): stage only units 254 (A-ks1 of 63) and 255 (B-ks1)
  SYNC("8") PHASE(0, 0, 16384, 0, 1, STGA(6, 4064))
  PHASE(0, 0, 16384, 4, 0, STGB(7, 4064))
  SYNC("8") PHASE(0, 32768, 49152, 0, 1, )
  PHASE(0, 32768, 49152, 4, 0, )
  // tile 63 (parity 1): drain
  SYNC("4") PHASE(65536, 0, 16384, 0, 1, )
  PHASE(65536, 0, 16384, 4, 0, )
  SYNC("0") PHASE(65536, 32768, 49152, 0, 1, )
  PHASE(65536, 32768, 49152, 4, 0, )

#undef KT
#undef PHASE
#undef SYNC
#undef STGB
#undef STGA

  // epilogue: C/D layout col=lane&15, row=(lane>>4)*4+j
#pragma unroll
  for (int mi = 0; mi < 8; mi++) {
#pragma unroll
    for (int ni = 0; ni < 4; ni++) {
      long col = n0 + wn * 64 + ni * 16 + lr;
      f32x4 v = acc[mi][ni];
#pragma unroll
      for (int j = 0; j < 4; j++) {
        long row = m0 + wm * 128 + mi * 16 + lg * 4 + j;
        if (CF) {
          CF[row * 4096 + col] = v[j];
        } else if (row < M1) {
          *(short*)(C + row * 4096 + col) = f2bf(v[j]);
        } else if (Cp != 0 && row < Mtot) {
          *(short*)(Cp + (row - M1) * 4096 + col) = f2bf(v[j]);
        }
      }
    }
  }
}

// ---------------------------------------------------------------------------
// RoPE in-place on q / k  ([2048][4096]), freqs f32.
// ---------------------------------------------------------------------------
__global__ __launch_bounds__(256) void rope_qk(
    bf16* __restrict__ Q, bf16* __restrict__ Kb,
    const float* __restrict__ FC, const float* __restrict__ FS)
{
  const int row = blockIdx.x;
  const int s = row & 1023;
  const int t = threadIdx.x;
  bf16* base = (blockIdx.y ? Kb : Q) + (long)row * 4096 + t * 16;
  short8 v0 = *(const short8*)base;
  short8 v1 = *(const short8*)(base + 8);
  const float* cp = FC + s * 64 + (t & 7) * 8;
  const float* sp = FS + s * 64 + (t & 7) * 8;
  f32x4 c0 = *(const f32x4*)cp;
  f32x4 c1 = *(const f32x4*)(cp + 4);
  f32x4 s0 = *(const f32x4*)sp;
  f32x4 s1 = *(const f32x4*)(sp + 4);
  short8 o0, o1;
#pragma unroll
  for (int j = 0; j < 4; j++) {
    float c = c0[j], sn = s0[j];
    float e = bf2f(v0[2 * j]), od = bf2f(v0[2 * j + 1]);
    o0[2 * j] = f2bf(e * c - od * sn);
    o0[2 * j + 1] = f2bf(e * sn + od * c);
    float c2 = c1[j], sn2 = s1[j];
    float e2 = bf2f(v1[2 * j]), od2 = bf2f(v1[2 * j + 1]);
    o1[2 * j] = f2bf(e2 * c2 - od2 * sn2);
    o1[2 * j + 1] = f2bf(e2 * sn2 + od2 * c2);
  }
  *(short8*)base = o0;
  *(short8*)(base + 8) = o1;
}

// ---------------------------------------------------------------------------
// V transpose: v[b][s][h][d] -> vT[bh][d][s]
// ---------------------------------------------------------------------------
__global__ __launch_bounds__(256) void transpose_v(
    const bf16* __restrict__ V, bf16* __restrict__ VT)
{
  __shared__ bf16 T[64 * 128];
  const int tid = threadIdx.x;
  const int st = blockIdx.x * 64, bh = blockIdx.y;
  const int b = bh >> 5, h = bh & 31;
  const bf16* src = V + ((long)(b * 1024 + st)) * 4096 + h * 128;
#pragma unroll
  for (int rr = 0; rr < 4; ++rr) {
    int i = tid + rr * 256;
    int s_l = i >> 4, c = i & 15;
    short8 v = *(const short8*)(src + (long)s_l * 4096 + c * 8);
    *(short8*)((char*)T + s_l * 256 + ((c ^ (s_l & 7)) * 16)) = v;
  }
  __syncthreads();
#pragma unroll
  for (int rr = 0; rr < 4; ++rr) {
    int i = tid + rr * 256;
    int d = i >> 3, cs = i & 7;
    short8 ov;
#pragma unroll
    for (int e = 0; e < 8; e++) {
      int s_l = cs * 8 + e;
      ov[e] = *(const short*)((char*)T + s_l * 256 + (((d >> 3) ^ (s_l & 7)) * 16) + (d & 7) * 2);
    }
    *(short8*)(VT + ((long)bh * 128 + d) * 1024 + st + cs * 8) = ov;
  }
}

// ---------------------------------------------------------------------------
// Flash attention, causal, + fused gated prompt attention. (unchanged, passing)
// ---------------------------------------------------------------------------
__global__ __launch_bounds__(256) void flash_attn(
    const bf16* __restrict__ Q, const bf16* __restrict__ Kg, const bf16* __restrict__ VT,
    const bf16* __restrict__ PK, const bf16* __restrict__ PV,
    const float* __restrict__ GATE, bf16* __restrict__ O)
{
  __shared__ bf16 Kl[32 * 128];
  __shared__ bf16 Vl[128 * 32];
  __shared__ bf16 PKl[16 * 128];
  __shared__ bf16 PVl[128 * 16];
  __shared__ bf16 Pl[4][16 * 32];
  const int tid = threadIdx.x, w = tid >> 6, l = tid & 63;
  const int lg = l >> 4, lr = l & 15;
  const int qb = blockIdx.x, bh = blockIdx.y;
  const int b = bh >> 5, h = bh & 31;
  const int q0 = qb * 64 + w * 16;

  short8 qf[4];
  {
    const bf16* qp = Q + ((long)(b * 1024 + q0 + lr)) * 4096 + h * 128 + lg * 8;
#pragma unroll
    for (int c = 0; c < 4; c++) qf[c] = *(const short8*)(qp + c * 32);
  }
  {
    int rowp = tid >> 4, pc = tid & 15, lc = pc ^ (rowp & 7);
    short8 v = {0, 0, 0, 0, 0, 0, 0, 0};
    if (rowp < 10) v = *(const short8*)(PK + (long)rowp * 4096 + h * 128 + lc * 8);
    *(short8*)((char*)PKl + tid * 16) = v;
  }
  {
    int d = tid >> 1, pb = (tid & 1) * 8;
#pragma unroll
    for (int e = 0; e < 8; e++) {
      int p = pb + e;
      short v = 0;
      if (p < 10) v = __builtin_bit_cast(short, PV[(long)p * 4096 + h * 128 + d]);
      *(short*)((char*)PVl + d * 32 + (((p >> 3) ^ (d & 1)) * 16) + (p & 7) * 2) = v;
    }
  }
  const float gate = GATE[h];

  f32x4 o[8];
#pragma unroll
  for (int i = 0; i < 8; i++) o[i] = (f32x4){0.f, 0.f, 0.f, 0.f};
  float m_[4] = {-1e30f, -1e30f, -1e30f, -1e30f};
  float l_[4] = {0.f, 0.f, 0.f, 0.f};

  const int nt = (qb + 1) * 2;
  const bf16* Kbase = Kg + ((long)b * 1024) * 4096 + h * 128;
  const bf16* Vbase = VT + ((long)bh) * 128 * 1024;
  const int cb1 = w * 64, cb2 = 256 + w * 64;
  const int iA = cb1 + l, iB = cb2 + l;
  bf16* pw = &Pl[w][0];

  for (int j = 0; j < nt; ++j) {
    __syncthreads();
    {
      const bf16* gA = Kbase + (long)(j * 32 + (iA >> 4)) * 4096 + ((iA & 15) ^ ((iA >> 4) & 7)) * 8;
      const bf16* gB = Kbase + (long)(j * 32 + (iB >> 4)) * 4096 + ((iB & 15) ^ ((iB >> 4) & 7)) * 8;
      gl_lds16(gA, Kl + cb1 * 8);
      gl_lds16(gB, Kl + cb2 * 8);
      const bf16* vA = Vbase + (long)(iA >> 2) * 1024 + j * 32 + ((iA & 3) ^ ((iA >> 2) & 3)) * 8;
      const bf16* vB = Vbase + (long)(iB >> 2) * 1024 + j * 32 + ((iB & 3) ^ ((iB >> 2) & 3)) * 8;
      gl_lds16(vA, Vl + cb1 * 8);
      gl_lds16(vB, Vl + cb2 * 8);
    }
    __syncthreads();

    f32x4 s[2];
#pragma unroll
    for (int ns = 0; ns < 2; ns++) {
      f32x4 a = (f32x4){0.f, 0.f, 0.f, 0.f};
      int krow = ns * 16 + lr;
      const char* kp = (const char*)Kl + krow * 256;
      int sw = krow & 7;
#pragma unroll
      for (int c = 0; c < 4; c++) {
        short8 kf = *(const short8*)(kp + (((c * 4 + lg) ^ sw) * 16));
        a = mfma16(qf[c], kf, a);
      }
      int key = j * 32 + krow;
#pragma unroll
      for (int r = 0; r < 4; r++) {
        int qr = q0 + lg * 4 + r;
        s[ns][r] = a[r] * SCALE_ + ((key <= qr) ? 0.0f : -1e30f);
      }
    }
    float mx[4], cor[4], sum[4];
#pragma unroll
    for (int r = 0; r < 4; r++) mx[r] = fmaxf(s[0][r], s[1][r]);
#pragma unroll
    for (int xm = 1; xm < 16; xm <<= 1)
#pragma unroll
      for (int r = 0; r < 4; r++) mx[r] = fmaxf(mx[r], __shfl_xor(mx[r], xm, 64));
#pragma unroll
    for (int r = 0; r < 4; r++) {
      float mn = fmaxf(m_[r], mx[r]);
      cor[r] = __expf(m_[r] - mn);
      m_[r] = mn;
      s[0][r] = __expf(s[0][r] - mn);
      s[1][r] = __expf(s[1][r] - mn);
      sum[r] = s[0][r] + s[1][r];
    }
#pragma unroll
    for (int xm = 1; xm < 16; xm <<= 1)
#pragma unroll
      for (int r = 0; r < 4; r++) sum[r] += __shfl_xor(sum[r], xm, 64);
#pragma unroll
    for (int r = 0; r < 4; r++) l_[r] = l_[r] * cor[r] + sum[r];
#pragma unroll
    for (int df = 0; df < 8; df++)
#pragma unroll
      for (int r = 0; r < 4; r++) o[df][r] *= cor[r];

#pragma unroll
    for (int ns = 0; ns < 2; ns++)
#pragma unroll
      for (int r = 0; r < 4; r++)
        *(short*)((char*)pw + ((lg * 4 + r) * 32 + ns * 16 + lr) * 2) = f2bf(s[ns][r]);
    asm volatile("s_waitcnt lgkmcnt(0)" ::: "memory");
    __builtin_amdgcn_sched_barrier(0);
    short8 pf = *(const short8*)(pw + lr * 32 + lg * 8);

#pragma unroll
    for (int df = 0; df < 8; df++) {
      int d = df * 16 + lr;
      short8 vf = *(const short8*)((const char*)Vl + d * 64 + ((lg ^ (d & 3)) * 16));
      o[df] = mfma16(pf, vf, o[df]);
    }
  }

  // ---- prompt attention ----
  f32x4 ps;
  {
    f32x4 a = (f32x4){0.f, 0.f, 0.f, 0.f};
    const char* kp = (const char*)PKl + lr * 256;
    int sw = lr & 7;
#pragma unroll
    for (int c = 0; c < 4; c++) {
      short8 kf = *(const short8*)(kp + (((c * 4 + lg) ^ sw) * 16));
      a = mfma16(qf[c], kf, a);
    }
#pragma unroll
    for (int r = 0; r < 4; r++) ps[r] = (lr < 10) ? a[r] * SCALE_ : -1e30f;
  }
  {
    float pm[4], pss[4];
#pragma unroll
    for (int r = 0; r < 4; r++) pm[r] = ps[r];
#pragma unroll
    for (int xm = 1; xm < 16; xm <<= 1)
#pragma unroll
      for (int r = 0; r < 4; r++) pm[r] = fmaxf(pm[r], __shfl_xor(pm[r], xm, 64));
#pragma unroll
    for (int r = 0; r < 4; r++) { ps[r] = __expf(ps[r] - pm[r]); pss[r] = ps[r]; }
#pragma unroll
    for (int xm = 1; xm < 16; xm <<= 1)
#pragma unroll
      for (int r = 0; r < 4; r++) pss[r] += __shfl_xor(pss[r], xm, 64);
#pragma unroll
    for (int r = 0; r < 4; r++) ps[r] = ps[r] / pss[r];
  }
#pragma unroll
  for (int r = 0; r < 4; r++) {
    *(short*)((char*)pw + ((lg * 4 + r) * 32 + lr) * 2) = f2bf(ps[r]);
    *(short*)((char*)pw + ((lg * 4 + r) * 32 + 16 + lr) * 2) = 0;
  }
  asm volatile("s_waitcnt lgkmcnt(0)" ::: "memory");
  __builtin_amdgcn_sched_barrier(0);
  short8 pf2 = *(const short8*)(pw + lr * 32 + lg * 8);
  f32x4 po[8];
#pragma unroll
  for (int df = 0; df < 8; df++) {
    int d = df * 16 + lr;
    short8 vf = {0, 0, 0, 0, 0, 0, 0, 0};
    if (lg < 2) vf = *(const short8*)((const char*)PVl + d * 32 + ((lg ^ (d & 1)) * 16));
    po[df] = mfma16(pf2, vf, (f32x4){0.f, 0.f, 0.f, 0.f});
  }

  bf16* op = O + ((long)(b * 1024 + q0 + lg * 4)) * 4096 + h * 128 + lr;
#pragma unroll
  for (int df = 0; df < 8; df++)
#pragma unroll
    for (int r = 0; r < 4; r++) {
      float val = o[df][r] / l_[r] + gate * po[df][r];
      *(short*)(op + (long)r * 4096 + df * 16) = f2bf(val);
    }
}

// ---------------------------------------------------------------------------
extern "C" void kernel_launch(void* const* d_in, const int* in_sizes, int n_in,
                              void* d_out, int out_size, void* d_ws, size_t ws_size,
                              hipStream_t stream) {
  (void)in_sizes; (void)n_in; (void)out_size; (void)ws_size;
  const float* x      = (const float*)d_in[0];
  const float* wq     = (const float*)d_in[1];
  const float* wk     = (const float*)d_in[2];
  const float* wv     = (const float*)d_in[3];
  const float* wo     = (const float*)d_in[4];
  const float* prompt = (const float*)d_in[5];
  const float* gate   = (const float*)d_in[6];
  const float* fcos   = (const float*)d_in[7];
  const float* fsin   = (const float*)d_in[8];
  float* out = (float*)d_out;
  char* ws = (char*)d_ws;

  size_t o = 0;
  bf16* xb  = (bf16*)(ws + o); o += (size_t)8388608 * 2;
  bf16* wqb = (bf16*)(ws + o); o += (size_t)16777216 * 2;
  bf16* wkb = (bf16*)(ws + o); o += (size_t)16777216 * 2;
  bf16* wvb = (bf16*)(ws + o); o += (size_t)16777216 * 2;
  bf16* wob = (bf16*)(ws + o); o += (size_t)16777216 * 2;
  bf16* pb  = (bf16*)(ws + o); o += (size_t)40960 * 2;
  bf16* q_ws  = (bf16*)(ws + o); o += (size_t)2048 * 4096 * 2;
  bf16* k_ws  = (bf16*)(ws + o); o += (size_t)2048 * 4096 * 2;
  bf16* v_ws  = (bf16*)(ws + o); o += (size_t)2048 * 4096 * 2;
  bf16* vT_ws = (bf16*)(ws + o); o += (size_t)2048 * 4096 * 2;
  bf16* pk_ws = (bf16*)(ws + o); o += (size_t)40960 * 2;
  bf16* pv_ws = (bf16*)(ws + o); o += (size_t)40960 * 2;
  bf16* attn_ws = v_ws;

  // 1. downcast inputs to bf16
  cvt6<<<dim3(36884), 256, 0, stream>>>(x, wq, wk, wv, wo, prompt,
                                        xb, wqb, wkb, wvb, wob, pb);
  // 2. QKV (+prompt K/V rows): 9 m-tiles x 16 n-tiles per z (144 % 8 == 0)
  gemm_bt<<<dim3(144, 1, 3), 512, 0, stream>>>(
      xb, pb, wqb, wkb, wvb, q_ws, k_ws, v_ws, pk_ws, pv_ws, (float*)0, 2048, 2058);
  // 3. RoPE on q, k
  rope_qk<<<dim3(2048, 2), 256, 0, stream>>>(q_ws, k_ws, fcos, fsin);
  // 4. V -> VT
  transpose_v<<<dim3(16, 64), 256, 0, stream>>>(v_ws, vT_ws);
  // 5. flash attention + gated prompt attention
  flash_attn<<<dim3(16, 64), 256, 0, stream>>>(
      q_ws, k_ws, vT_ws, pk_ws, pv_ws, gate, attn_ws);
  // 6. output projection (f32 out): 8 x 16 tiles (128 % 8 == 0)
  gemm_bt<<<dim3(128, 1, 1), 512, 0, stream>>>(
      attn_ws, (const bf16*)0, wob, wob, wob, q_ws, q_ws, q_ws,
      (bf16*)0, (bf16*)0, out, 2048, 2048);
}